// Round 7
// baseline (370.502 us; speedup 1.0000x reference)
//
#include <hip/hip_runtime.h>

#define N_NODES 50000
#define N_EDGES 800000
#define IN_DIM 16
#define OUT_DIM 16
#define N_RELS 90
#define N_BASES 30

#define CAP 64          // 8B entries -> 512B/node row

#define PREP_BLOCKS 91   // 91*256 = 23296 >= 23088
#define DOTS_BLOCKS 196  // 196*256 = 50176 >= 50000
#define ZERO_BLOCKS 196
#define HZ_BLOCKS 782    // 782*256 float4 >= 200000 float4 (zero hout)

#define ROUTE_BLOCKS 3125    // 1 edge/thread, 256/block
#define RNODES_PER_BLK 64    // reduce: 1024 thr / 16 lanes-per-node
#define REDUCE_BLOCKS 782    // 782*64 = 50048 >= 50000

__device__ __forceinline__ float4 shfl_xor4(float4 v, int m) {
    float4 r;
    r.x = __shfl_xor(v.x, m); r.y = __shfl_xor(v.y, m);
    r.z = __shfl_xor(v.z, m); r.w = __shfl_xor(v.w, m);
    return r;
}

// ---------------------------------------------------------------------------
// Setup: [0,91) prep Wrel+avec; [91,287) node dots s1/s3; [287,483) zero cnt;
// [483,1265) zero hout.
// ---------------------------------------------------------------------------
__global__ __launch_bounds__(256) void setup_kernel(
    const float* __restrict__ Ws,
    const float* __restrict__ Wa,
    const float* __restrict__ weight,
    const float* __restrict__ w_comp,
    const float* __restrict__ h,
    float* __restrict__ Wrel,
    float* __restrict__ avec,
    float* __restrict__ s1,
    float* __restrict__ s3,
    int* __restrict__ cnt,
    float* __restrict__ hout)
{
    int b = blockIdx.x;
    if (b < PREP_BLOCKS) {
        int f = b * 256 + threadIdx.x;
        if (f < N_RELS * IN_DIM * OUT_DIM) {
            int a   = f / (N_RELS * OUT_DIM);
            int rem = f % (N_RELS * OUT_DIM);
            int r   = rem / OUT_DIM;
            int o   = rem % OUT_DIM;
            float acc = 0.f;
            #pragma unroll
            for (int bb = 0; bb < N_BASES; ++bb)
                acc += w_comp[r * N_BASES + bb] * weight[a * (N_BASES * OUT_DIM) + bb * OUT_DIM + o];
            Wrel[f] = acc;
        } else if (f < N_RELS * IN_DIM * OUT_DIM + 48) {
            int g = f - N_RELS * IN_DIM * OUT_DIM;
            int k = g / IN_DIM;
            int i = g % IN_DIM;
            float acc = 0.f;
            #pragma unroll
            for (int o = 0; o < OUT_DIM; ++o)
                acc += Wa[k * OUT_DIM + o] * Ws[o * IN_DIM + i];
            avec[g] = acc;
        }
    } else if (b < PREP_BLOCKS + DOTS_BLOCKS) {
        __shared__ float la[48];
        if (threadIdx.x < 48) {
            int k = threadIdx.x / IN_DIM;
            int i = threadIdx.x % IN_DIM;
            float acc = 0.f;
            #pragma unroll
            for (int o = 0; o < OUT_DIM; ++o)
                acc += Wa[k * OUT_DIM + o] * Ws[o * IN_DIM + i];
            la[threadIdx.x] = acc;
        }
        __syncthreads();
        int n = (b - PREP_BLOCKS) * 256 + threadIdx.x;
        if (n >= N_NODES) return;
        const float4* p = (const float4*)(h + (size_t)n * IN_DIM);
        float d1 = 0.f, d3 = 0.f;
        #pragma unroll
        for (int i = 0; i < 4; ++i) {
            float4 v = p[i];
            d1 += v.x * la[4*i+0] + v.y * la[4*i+1] + v.z * la[4*i+2] + v.w * la[4*i+3];
            d3 += v.x * la[32+4*i+0] + v.y * la[32+4*i+1] + v.z * la[32+4*i+2] + v.w * la[32+4*i+3];
        }
        s1[n] = d1;
        s3[n] = d3;
    } else if (b < PREP_BLOCKS + DOTS_BLOCKS + ZERO_BLOCKS) {
        int n = (b - PREP_BLOCKS - DOTS_BLOCKS) * 256 + threadIdx.x;
        if (n < N_NODES) cnt[n] = 0;
    } else {
        int idx = (b - PREP_BLOCKS - DOTS_BLOCKS - ZERO_BLOCKS) * 256 + threadIdx.x;
        if (idx < N_NODES * OUT_DIM / 4) {
            float4 z = {0.f, 0.f, 0.f, 0.f};
            ((float4*)hout)[idx] = z;
        }
    }
}

// ---------------------------------------------------------------------------
// Route: 1 edge/thread, contiguous (coalesced idx + he stream). Only TWO
// random memory ops per edge: the cnt atomic and the 8B entry store.
// Entry carries pd = he[e] . a_edge; score finalized in reduce.
// ---------------------------------------------------------------------------
__global__ __launch_bounds__(256) void route_kernel(
    const float* __restrict__ h,
    const float* __restrict__ he,
    const int* __restrict__ src,
    const int* __restrict__ dst,
    const int* __restrict__ rel,
    const float* __restrict__ Wrel,
    const float* __restrict__ avec,
    const float* __restrict__ s1,
    const float* __restrict__ s3,
    int* __restrict__ cnt,
    uint2* __restrict__ bucket,
    float* __restrict__ hout)
{
    int e = blockIdx.x * 256 + threadIdx.x;
    if (e >= N_EDGES) return;
    int s = src[e], d = dst[e], r = rel[e];

    const float4* hep = (const float4*)(he + (size_t)e * IN_DIM);
    const float4* ap  = (const float4*)(avec + 16);
    float pd = 0.f;
    #pragma unroll
    for (int i = 0; i < 4; ++i) {
        float4 v = hep[i];
        float4 a = ap[i];
        pd += v.x * a.x + v.y * a.y + v.z * a.z + v.w * a.w;
    }

    int slot = atomicAdd(&cnt[d], 1);
    if (slot < CAP) {
        uint2 ent;
        ent.x = ((unsigned)r << 16) | (unsigned)s;   // s < 50000 < 2^16, r < 90
        ent.y = __float_as_uint(pd);
        bucket[(size_t)d * CAP + slot] = ent;
    } else {
        // rare/never: full message from global Wrel (L2-hot), full score here
        float score = s1[s] + s3[d] + pd;
        float hs[16];
        const float4* hp = (const float4*)(h + (size_t)s * IN_DIM);
        #pragma unroll
        for (int i = 0; i < 4; ++i) {
            float4 v = hp[i];
            hs[4*i+0] = v.x; hs[4*i+1] = v.y; hs[4*i+2] = v.z; hs[4*i+3] = v.w;
        }
        const float* W = Wrel + (size_t)r * 256;
        float* outp = hout + (size_t)d * OUT_DIM;
        #pragma unroll
        for (int o = 0; o < OUT_DIM; ++o) {
            float acc = 0.f;
            #pragma unroll
            for (int i = 0; i < IN_DIM; ++i) acc += hs[i] * W[i * OUT_DIM + o];
            atomicAdd(outp + o, acc * score);
        }
    }
}

// ---------------------------------------------------------------------------
// Reduce+BMM: NO LDS. W read directly from global Wrel (90KB, L2/L3-hot;
// each quad reads contiguous 64B lines). Zero LDS + <=64 VGPR
// (__launch_bounds__(1024,8)) -> 2 blocks/CU = 32 waves/CU: double the
// latency hiding for the random h/s1 gathers, no bank conflicts, no
// staging barrier. 16 lanes/node (q = output quarter, p = entry stream),
// 2-entry batch per stream -> 8 entries in flight per node. XOR-row
// addressing for the quad transpose (no cndmask selects); hq pre-scaled
// by score. Final cross-stream butterfly (xor 4,8).
// ---------------------------------------------------------------------------
__global__ __launch_bounds__(1024, 8) void reduce_bmm_kernel(
    const float* __restrict__ h,
    const float* __restrict__ Wrel,
    const float* __restrict__ s1,
    const float* __restrict__ s3,
    const uint2* __restrict__ bucket,
    const int* __restrict__ cnt,
    float* __restrict__ hout)
{
    const int l = threadIdx.x & 15;
    const int q = l & 3;
    const int p = l >> 2;               // 0..3: entry stream
    const int n = blockIdx.x * RNODES_PER_BLK + (threadIdx.x >> 4);
    if (n >= N_NODES) return;

    int deg = cnt[n];
    int m = deg > CAP ? CAP : deg;
    const uint2* ep = bucket + (size_t)n * CAP;
    float s3n = s3[n];
    float4 acc = {0.f, 0.f, 0.f, 0.f};

    for (int j0 = 0; j0 < m; j0 += 8) {
        uint2 ent[2];
        float4 hq[2];
        float s1v[2];
        bool val[2];

        // [1] entry loads (4 q-lanes share addr -> broadcast; slot 0 is
        //     valid whenever the loop is entered)
        #pragma unroll
        for (int k = 0; k < 2; ++k) {
            int j = j0 + p * 2 + k;
            val[k] = (j < m);
            ent[k] = ep[val[k] ? j : 0];
        }

        // [2] gathers: h[src] 16B/lane + s1[src] 4B (quad-broadcast);
        //     8 independent chains per node in flight
        #pragma unroll
        for (int k = 0; k < 2; ++k) {
            int sidx = ent[k].x & 0xFFFF;
            hq[k]  = *(const float4*)(h + (size_t)sidx * IN_DIM + q * 4);
            s1v[k] = s1[sidx];
        }

        // [3] process (val[k] uniform across the 4 q-lanes of (n,p))
        #pragma unroll
        for (int k = 0; k < 2; ++k) {
            if (!val[k]) continue;
            unsigned rr = ent[k].x >> 16;
            float score = s1v[k] + s3n + __uint_as_float(ent[k].y);
            float4 hx = hq[k];
            hx.x *= score; hx.y *= score; hx.z *= score; hx.w *= score;

            const float* wb = Wrel + (size_t)rr * 256 + q * 4;
            #pragma unroll
            for (int mm = 0; mm < 4; ++mm) {
                float4 vm = (mm == 0) ? hx : shfl_xor4(hx, mm);
                const float* wrow = wb + (((unsigned)(q ^ mm)) << 6);
                float4 w0 = *(const float4*)(wrow +  0);
                float4 w1 = *(const float4*)(wrow + 16);
                float4 w2 = *(const float4*)(wrow + 32);
                float4 w3 = *(const float4*)(wrow + 48);
                acc.x += vm.x*w0.x + vm.y*w1.x + vm.z*w2.x + vm.w*w3.x;
                acc.y += vm.x*w0.y + vm.y*w1.y + vm.z*w2.y + vm.w*w3.y;
                acc.z += vm.x*w0.z + vm.y*w1.z + vm.z*w2.z + vm.w*w3.z;
                acc.w += vm.x*w0.w + vm.y*w1.w + vm.z*w2.w + vm.w*w3.w;
            }
        }
    }

    // cross-stream butterfly (within the node's 16 lanes)
    acc.x += __shfl_xor(acc.x, 4); acc.y += __shfl_xor(acc.y, 4);
    acc.z += __shfl_xor(acc.z, 4); acc.w += __shfl_xor(acc.w, 4);
    acc.x += __shfl_xor(acc.x, 8); acc.y += __shfl_xor(acc.y, 8);
    acc.z += __shfl_xor(acc.z, 8); acc.w += __shfl_xor(acc.w, 8);

    if (p == 0) {
        float* outp = hout + (size_t)n * OUT_DIM + q * 4;
        if (deg <= CAP) {
            *(float4*)outp = acc;
        } else {
            atomicAdd(outp + 0, acc.x);
            atomicAdd(outp + 1, acc.y);
            atomicAdd(outp + 2, acc.z);
            atomicAdd(outp + 3, acc.w);
        }
    }
}

// ===========================================================================
// Fallback (ws too small): direct atomic scatter (known-correct).
// ===========================================================================
__global__ __launch_bounds__(256) void prep_kernel(
    const float* __restrict__ Ws, const float* __restrict__ Wa,
    const float* __restrict__ weight, const float* __restrict__ w_comp,
    float* __restrict__ Wrel, float* __restrict__ avec)
{
    int f = blockIdx.x * blockDim.x + threadIdx.x;
    if (f < N_RELS * IN_DIM * OUT_DIM) {
        int a   = f / (N_RELS * OUT_DIM);
        int rem = f % (N_RELS * OUT_DIM);
        int r   = rem / OUT_DIM;
        int o   = rem % OUT_DIM;
        float acc = 0.f;
        #pragma unroll
        for (int b = 0; b < N_BASES; ++b)
            acc += w_comp[r * N_BASES + b] * weight[a * (N_BASES * OUT_DIM) + b * OUT_DIM + o];
        Wrel[f] = acc;
    } else if (f < N_RELS * IN_DIM * OUT_DIM + 48) {
        int g = f - N_RELS * IN_DIM * OUT_DIM;
        int k = g / IN_DIM;
        int i = g % IN_DIM;
        float acc = 0.f;
        #pragma unroll
        for (int o = 0; o < OUT_DIM; ++o)
            acc += Wa[k * OUT_DIM + o] * Ws[o * IN_DIM + i];
        avec[g] = acc;
    }
}

__global__ __launch_bounds__(256) void edge_atomic_kernel(
    const float* __restrict__ h,
    const float* __restrict__ he,
    const int* __restrict__ src,
    const int* __restrict__ dst,
    const int* __restrict__ rel,
    const float* __restrict__ Wrel,
    const float* __restrict__ avec,
    float* __restrict__ hout)
{
    int e = blockIdx.x * blockDim.x + threadIdx.x;
    if (e >= N_EDGES) return;
    int s = src[e], d = dst[e], r = rel[e];
    float hs[IN_DIM];
    const float4* p = (const float4*)(h + (size_t)s * IN_DIM);
    #pragma unroll
    for (int i = 0; i < 4; ++i) {
        float4 v = p[i];
        hs[4*i+0] = v.x; hs[4*i+1] = v.y; hs[4*i+2] = v.z; hs[4*i+3] = v.w;
    }
    float score = 0.f;
    #pragma unroll
    for (int i = 0; i < IN_DIM; ++i) score += hs[i] * avec[i];
    const float4* qe = (const float4*)(he + (size_t)e * IN_DIM);
    #pragma unroll
    for (int i = 0; i < 4; ++i) {
        float4 v = qe[i];
        score += v.x * avec[16+4*i] + v.y * avec[17+4*i] + v.z * avec[18+4*i] + v.w * avec[19+4*i];
    }
    const float4* pd = (const float4*)(h + (size_t)d * IN_DIM);
    #pragma unroll
    for (int i = 0; i < 4; ++i) {
        float4 v = pd[i];
        score += v.x * avec[32+4*i] + v.y * avec[33+4*i] + v.z * avec[34+4*i] + v.w * avec[35+4*i];
    }
    float acc[OUT_DIM];
    #pragma unroll
    for (int o = 0; o < OUT_DIM; ++o) acc[o] = 0.f;
    const float* W = Wrel + (size_t)r * 256;
    #pragma unroll
    for (int i = 0; i < IN_DIM; ++i) {
        float hv = hs[i];
        #pragma unroll
        for (int o = 0; o < OUT_DIM; ++o) acc[o] += hv * W[i * OUT_DIM + o];
    }
    float* outp = hout + (size_t)d * OUT_DIM;
    #pragma unroll
    for (int o = 0; o < OUT_DIM; ++o) atomicAdd(outp + o, acc[o] * score);
}

extern "C" void kernel_launch(void* const* d_in, const int* in_sizes, int n_in,
                              void* d_out, int out_size, void* d_ws, size_t ws_size,
                              hipStream_t stream) {
    const float* h      = (const float*)d_in[0];
    const float* he     = (const float*)d_in[1];
    const float* Ws     = (const float*)d_in[2];
    const float* Wa     = (const float*)d_in[3];
    const float* weight = (const float*)d_in[4];
    const float* w_comp = (const float*)d_in[5];
    const int*   src    = (const int*)d_in[6];
    const int*   dst    = (const int*)d_in[7];
    const int*   rel    = (const int*)d_in[8];
    float* hout = (float*)d_out;

    // ws layout (float offsets)
    const size_t OFF_WREL   = 0;         // 23040 f
    const size_t OFF_AVEC   = 23040;     // 48 f (+16 pad)
    const size_t OFF_S1     = 23104;     // 50000 f
    const size_t OFF_S3     = 73104;     // 50000 f
    const size_t OFF_CNT    = 123104;    // 50000 i
    const size_t OFF_BUCKET = 173104;    // N*CAP uint2 (8B aligned)
    const size_t NEED_BUCKET = OFF_BUCKET * 4 + (size_t)N_NODES * CAP * sizeof(uint2);

    float* wsf  = (float*)d_ws;
    float* Wrel = wsf + OFF_WREL;
    float* avec = wsf + OFF_AVEC;
    float* s1   = wsf + OFF_S1;
    float* s3   = wsf + OFF_S3;
    int* cnt    = (int*)(wsf + OFF_CNT);

    if (ws_size >= NEED_BUCKET) {
        uint2* bucket = (uint2*)(wsf + OFF_BUCKET);

        setup_kernel<<<PREP_BLOCKS + DOTS_BLOCKS + ZERO_BLOCKS + HZ_BLOCKS, 256, 0, stream>>>(
            Ws, Wa, weight, w_comp, h, Wrel, avec, s1, s3, cnt, hout);
        route_kernel<<<ROUTE_BLOCKS, 256, 0, stream>>>(
            h, he, src, dst, rel, Wrel, avec, s1, s3, cnt, bucket, hout);
        reduce_bmm_kernel<<<REDUCE_BLOCKS, 1024, 0, stream>>>(
            h, Wrel, s1, s3, bucket, cnt, hout);
    } else {
        hipMemsetAsync(d_out, 0, (size_t)out_size * sizeof(float), stream);
        int total = N_RELS * IN_DIM * OUT_DIM + 48;
        prep_kernel<<<(total + 255) / 256, 256, 0, stream>>>(Ws, Wa, weight, w_comp, Wrel, avec);
        edge_atomic_kernel<<<(N_EDGES + 255) / 256, 256, 0, stream>>>(
            h, he, src, dst, rel, Wrel, avec, hout);
    }
}

// Round 8
// 248.340 us; speedup vs baseline: 1.4919x; 1.4919x over previous
//
#include <hip/hip_runtime.h>

#define N_NODES 50000
#define N_EDGES 800000
#define IN_DIM 16
#define OUT_DIM 16
#define N_RELS 90
#define N_BASES 30

#define CAP 64          // 8B entries -> 512B/node row

#define PREP_BLOCKS 91   // 91*256 = 23296 >= 23088
#define DOTS_BLOCKS 196  // 196*256 = 50176 >= 50000
#define ZERO_BLOCKS 196
#define HZ_BLOCKS 782    // 782*256 float4 >= 200000 float4 (zero hout)

#define ROUTE_BLOCKS 3125    // 1 edge/thread, 256/block
#define RNODES_PER_BLK 64    // reduce: 1024 thr / 16 lanes-per-node
#define REDUCE_BLOCKS 782    // 782*64 = 50048 >= 50000

__device__ __forceinline__ float4 shfl_xor4(float4 v, int m) {
    float4 r;
    r.x = __shfl_xor(v.x, m); r.y = __shfl_xor(v.y, m);
    r.z = __shfl_xor(v.z, m); r.w = __shfl_xor(v.w, m);
    return r;
}

// ---------------------------------------------------------------------------
// Setup: [0,91) prep Wrel+avec; [91,287) node dots s1/s3; [287,483) zero cnt;
// [483,1265) zero hout.
// ---------------------------------------------------------------------------
__global__ __launch_bounds__(256) void setup_kernel(
    const float* __restrict__ Ws,
    const float* __restrict__ Wa,
    const float* __restrict__ weight,
    const float* __restrict__ w_comp,
    const float* __restrict__ h,
    float* __restrict__ Wrel,
    float* __restrict__ avec,
    float* __restrict__ s1,
    float* __restrict__ s3,
    int* __restrict__ cnt,
    float* __restrict__ hout)
{
    int b = blockIdx.x;
    if (b < PREP_BLOCKS) {
        int f = b * 256 + threadIdx.x;
        if (f < N_RELS * IN_DIM * OUT_DIM) {
            int a   = f / (N_RELS * OUT_DIM);
            int rem = f % (N_RELS * OUT_DIM);
            int r   = rem / OUT_DIM;
            int o   = rem % OUT_DIM;
            float acc = 0.f;
            #pragma unroll
            for (int bb = 0; bb < N_BASES; ++bb)
                acc += w_comp[r * N_BASES + bb] * weight[a * (N_BASES * OUT_DIM) + bb * OUT_DIM + o];
            Wrel[f] = acc;
        } else if (f < N_RELS * IN_DIM * OUT_DIM + 48) {
            int g = f - N_RELS * IN_DIM * OUT_DIM;
            int k = g / IN_DIM;
            int i = g % IN_DIM;
            float acc = 0.f;
            #pragma unroll
            for (int o = 0; o < OUT_DIM; ++o)
                acc += Wa[k * OUT_DIM + o] * Ws[o * IN_DIM + i];
            avec[g] = acc;
        }
    } else if (b < PREP_BLOCKS + DOTS_BLOCKS) {
        __shared__ float la[48];
        if (threadIdx.x < 48) {
            int k = threadIdx.x / IN_DIM;
            int i = threadIdx.x % IN_DIM;
            float acc = 0.f;
            #pragma unroll
            for (int o = 0; o < OUT_DIM; ++o)
                acc += Wa[k * OUT_DIM + o] * Ws[o * IN_DIM + i];
            la[threadIdx.x] = acc;
        }
        __syncthreads();
        int n = (b - PREP_BLOCKS) * 256 + threadIdx.x;
        if (n >= N_NODES) return;
        const float4* p = (const float4*)(h + (size_t)n * IN_DIM);
        float d1 = 0.f, d3 = 0.f;
        #pragma unroll
        for (int i = 0; i < 4; ++i) {
            float4 v = p[i];
            d1 += v.x * la[4*i+0] + v.y * la[4*i+1] + v.z * la[4*i+2] + v.w * la[4*i+3];
            d3 += v.x * la[32+4*i+0] + v.y * la[32+4*i+1] + v.z * la[32+4*i+2] + v.w * la[32+4*i+3];
        }
        s1[n] = d1;
        s3[n] = d3;
    } else if (b < PREP_BLOCKS + DOTS_BLOCKS + ZERO_BLOCKS) {
        int n = (b - PREP_BLOCKS - DOTS_BLOCKS) * 256 + threadIdx.x;
        if (n < N_NODES) cnt[n] = 0;
    } else {
        int idx = (b - PREP_BLOCKS - DOTS_BLOCKS - ZERO_BLOCKS) * 256 + threadIdx.x;
        if (idx < N_NODES * OUT_DIM / 4) {
            float4 z = {0.f, 0.f, 0.f, 0.f};
            ((float4*)hout)[idx] = z;
        }
    }
}

// ---------------------------------------------------------------------------
// Route: 1 edge/thread, contiguous (coalesced idx + he stream). Only TWO
// random memory ops per edge: the cnt atomic and the 8B entry store.
// Entry carries pd = he[e] . a_edge; score finalized in reduce.
// ---------------------------------------------------------------------------
__global__ __launch_bounds__(256) void route_kernel(
    const float* __restrict__ h,
    const float* __restrict__ he,
    const int* __restrict__ src,
    const int* __restrict__ dst,
    const int* __restrict__ rel,
    const float* __restrict__ Wrel,
    const float* __restrict__ avec,
    const float* __restrict__ s1,
    const float* __restrict__ s3,
    int* __restrict__ cnt,
    uint2* __restrict__ bucket,
    float* __restrict__ hout)
{
    int e = blockIdx.x * 256 + threadIdx.x;
    if (e >= N_EDGES) return;
    int s = src[e], d = dst[e], r = rel[e];

    const float4* hep = (const float4*)(he + (size_t)e * IN_DIM);
    const float4* ap  = (const float4*)(avec + 16);
    float pd = 0.f;
    #pragma unroll
    for (int i = 0; i < 4; ++i) {
        float4 v = hep[i];
        float4 a = ap[i];
        pd += v.x * a.x + v.y * a.y + v.z * a.z + v.w * a.w;
    }

    int slot = atomicAdd(&cnt[d], 1);
    if (slot < CAP) {
        uint2 ent;
        ent.x = ((unsigned)r << 16) | (unsigned)s;   // s < 50000 < 2^16, r < 90
        ent.y = __float_as_uint(pd);
        bucket[(size_t)d * CAP + slot] = ent;
    } else {
        // rare/never: full message from global Wrel (L2-hot), full score here
        float score = s1[s] + s3[d] + pd;
        float hs[16];
        const float4* hp = (const float4*)(h + (size_t)s * IN_DIM);
        #pragma unroll
        for (int i = 0; i < 4; ++i) {
            float4 v = hp[i];
            hs[4*i+0] = v.x; hs[4*i+1] = v.y; hs[4*i+2] = v.z; hs[4*i+3] = v.w;
        }
        const float* W = Wrel + (size_t)r * 256;
        float* outp = hout + (size_t)d * OUT_DIM;
        #pragma unroll
        for (int o = 0; o < OUT_DIM; ++o) {
            float acc = 0.f;
            #pragma unroll
            for (int i = 0; i < IN_DIM; ++i) acc += hs[i] * W[i * OUT_DIM + o];
            atomicAdd(outp + o, acc * score);
        }
    }
}

// ---------------------------------------------------------------------------
// Reduce+BMM: W read directly from global Wrel (90KB: L1 ~30% + L2-resident).
// NO LDS, NO launch-bounds occupancy cap (round-7 lesson: __launch_bounds__
// (1024,8) forced VGPR=32 -> scratch spills -> 158MB of spill writes).
// Load->FMA interleave keeps ~1 W-float4 live at a time, so natural VGPR
// stays ~50-80 with zero spill. 16 lanes/node (q = output quarter, p = entry
// stream), 2-entry batch per stream -> 8 entries in flight per node. XOR-row
// addressing for the quad transpose; hq pre-scaled by score (quad-uniform).
// Final cross-stream butterfly (xor 4,8).
// ---------------------------------------------------------------------------
__global__ __launch_bounds__(1024) void reduce_bmm_kernel(
    const float* __restrict__ h,
    const float* __restrict__ Wrel,
    const float* __restrict__ s1,
    const float* __restrict__ s3,
    const uint2* __restrict__ bucket,
    const int* __restrict__ cnt,
    float* __restrict__ hout)
{
    const int l = threadIdx.x & 15;
    const int q = l & 3;
    const int p = l >> 2;               // 0..3: entry stream
    const int n = blockIdx.x * RNODES_PER_BLK + (threadIdx.x >> 4);
    if (n >= N_NODES) return;

    int deg = cnt[n];
    int m = deg > CAP ? CAP : deg;
    const uint2* ep = bucket + (size_t)n * CAP;
    float s3n = s3[n];
    float4 acc = {0.f, 0.f, 0.f, 0.f};

    for (int j0 = 0; j0 < m; j0 += 8) {
        uint2 ent[2];
        float4 hq[2];
        float s1v[2];
        bool val[2];

        // [1] entry loads (4 q-lanes share addr -> broadcast; slot 0 is
        //     valid whenever the loop is entered)
        #pragma unroll
        for (int k = 0; k < 2; ++k) {
            int j = j0 + p * 2 + k;
            val[k] = (j < m);
            ent[k] = ep[val[k] ? j : 0];
        }

        // [2] gathers: h[src] 16B/lane + s1[src] 4B (quad-broadcast);
        //     8 independent chains per node in flight
        #pragma unroll
        for (int k = 0; k < 2; ++k) {
            int sidx = ent[k].x & 0xFFFF;
            hq[k]  = *(const float4*)(h + (size_t)sidx * IN_DIM + q * 4);
            s1v[k] = s1[sidx];
        }

        // [3] process (val[k] uniform across the 4 q-lanes of (n,p))
        #pragma unroll
        for (int k = 0; k < 2; ++k) {
            if (!val[k]) continue;
            unsigned rr = ent[k].x >> 16;
            float score = s1v[k] + s3n + __uint_as_float(ent[k].y);
            float4 hx = hq[k];
            hx.x *= score; hx.y *= score; hx.z *= score; hx.w *= score;

            const float* wb = Wrel + (size_t)rr * 256 + q * 4;
            #pragma unroll
            for (int mm = 0; mm < 4; ++mm) {
                float4 vm = (mm == 0) ? hx : shfl_xor4(hx, mm);
                const float* wrow = wb + (((unsigned)(q ^ mm)) << 6);
                // load -> consume immediately: at most one W float4 live
                float4 w;
                w = *(const float4*)(wrow +  0);
                acc.x += vm.x*w.x; acc.y += vm.x*w.y; acc.z += vm.x*w.z; acc.w += vm.x*w.w;
                w = *(const float4*)(wrow + 16);
                acc.x += vm.y*w.x; acc.y += vm.y*w.y; acc.z += vm.y*w.z; acc.w += vm.y*w.w;
                w = *(const float4*)(wrow + 32);
                acc.x += vm.z*w.x; acc.y += vm.z*w.y; acc.z += vm.z*w.z; acc.w += vm.z*w.w;
                w = *(const float4*)(wrow + 48);
                acc.x += vm.w*w.x; acc.y += vm.w*w.y; acc.z += vm.w*w.z; acc.w += vm.w*w.w;
            }
        }
    }

    // cross-stream butterfly (within the node's 16 lanes)
    acc.x += __shfl_xor(acc.x, 4); acc.y += __shfl_xor(acc.y, 4);
    acc.z += __shfl_xor(acc.z, 4); acc.w += __shfl_xor(acc.w, 4);
    acc.x += __shfl_xor(acc.x, 8); acc.y += __shfl_xor(acc.y, 8);
    acc.z += __shfl_xor(acc.z, 8); acc.w += __shfl_xor(acc.w, 8);

    if (p == 0) {
        float* outp = hout + (size_t)n * OUT_DIM + q * 4;
        if (deg <= CAP) {
            *(float4*)outp = acc;
        } else {
            atomicAdd(outp + 0, acc.x);
            atomicAdd(outp + 1, acc.y);
            atomicAdd(outp + 2, acc.z);
            atomicAdd(outp + 3, acc.w);
        }
    }
}

// ===========================================================================
// Fallback (ws too small): direct atomic scatter (known-correct).
// ===========================================================================
__global__ __launch_bounds__(256) void prep_kernel(
    const float* __restrict__ Ws, const float* __restrict__ Wa,
    const float* __restrict__ weight, const float* __restrict__ w_comp,
    float* __restrict__ Wrel, float* __restrict__ avec)
{
    int f = blockIdx.x * blockDim.x + threadIdx.x;
    if (f < N_RELS * IN_DIM * OUT_DIM) {
        int a   = f / (N_RELS * OUT_DIM);
        int rem = f % (N_RELS * OUT_DIM);
        int r   = rem / OUT_DIM;
        int o   = rem % OUT_DIM;
        float acc = 0.f;
        #pragma unroll
        for (int b = 0; b < N_BASES; ++b)
            acc += w_comp[r * N_BASES + b] * weight[a * (N_BASES * OUT_DIM) + b * OUT_DIM + o];
        Wrel[f] = acc;
    } else if (f < N_RELS * IN_DIM * OUT_DIM + 48) {
        int g = f - N_RELS * IN_DIM * OUT_DIM;
        int k = g / IN_DIM;
        int i = g % IN_DIM;
        float acc = 0.f;
        #pragma unroll
        for (int o = 0; o < OUT_DIM; ++o)
            acc += Wa[k * OUT_DIM + o] * Ws[o * IN_DIM + i];
        avec[g] = acc;
    }
}

__global__ __launch_bounds__(256) void edge_atomic_kernel(
    const float* __restrict__ h,
    const float* __restrict__ he,
    const int* __restrict__ src,
    const int* __restrict__ dst,
    const int* __restrict__ rel,
    const float* __restrict__ Wrel,
    const float* __restrict__ avec,
    float* __restrict__ hout)
{
    int e = blockIdx.x * blockDim.x + threadIdx.x;
    if (e >= N_EDGES) return;
    int s = src[e], d = dst[e], r = rel[e];
    float hs[IN_DIM];
    const float4* p = (const float4*)(h + (size_t)s * IN_DIM);
    #pragma unroll
    for (int i = 0; i < 4; ++i) {
        float4 v = p[i];
        hs[4*i+0] = v.x; hs[4*i+1] = v.y; hs[4*i+2] = v.z; hs[4*i+3] = v.w;
    }
    float score = 0.f;
    #pragma unroll
    for (int i = 0; i < IN_DIM; ++i) score += hs[i] * avec[i];
    const float4* qe = (const float4*)(he + (size_t)e * IN_DIM);
    #pragma unroll
    for (int i = 0; i < 4; ++i) {
        float4 v = qe[i];
        score += v.x * avec[16+4*i] + v.y * avec[17+4*i] + v.z * avec[18+4*i] + v.w * avec[19+4*i];
    }
    const float4* pd = (const float4*)(h + (size_t)d * IN_DIM);
    #pragma unroll
    for (int i = 0; i < 4; ++i) {
        float4 v = pd[i];
        score += v.x * avec[32+4*i] + v.y * avec[33+4*i] + v.z * avec[34+4*i] + v.w * avec[35+4*i];
    }
    float acc[OUT_DIM];
    #pragma unroll
    for (int o = 0; o < OUT_DIM; ++o) acc[o] = 0.f;
    const float* W = Wrel + (size_t)r * 256;
    #pragma unroll
    for (int i = 0; i < IN_DIM; ++i) {
        float hv = hs[i];
        #pragma unroll
        for (int o = 0; o < OUT_DIM; ++o) acc[o] += hv * W[i * OUT_DIM + o];
    }
    float* outp = hout + (size_t)d * OUT_DIM;
    #pragma unroll
    for (int o = 0; o < OUT_DIM; ++o) atomicAdd(outp + o, acc[o] * score);
}

extern "C" void kernel_launch(void* const* d_in, const int* in_sizes, int n_in,
                              void* d_out, int out_size, void* d_ws, size_t ws_size,
                              hipStream_t stream) {
    const float* h      = (const float*)d_in[0];
    const float* he     = (const float*)d_in[1];
    const float* Ws     = (const float*)d_in[2];
    const float* Wa     = (const float*)d_in[3];
    const float* weight = (const float*)d_in[4];
    const float* w_comp = (const float*)d_in[5];
    const int*   src    = (const int*)d_in[6];
    const int*   dst    = (const int*)d_in[7];
    const int*   rel    = (const int*)d_in[8];
    float* hout = (float*)d_out;

    // ws layout (float offsets)
    const size_t OFF_WREL   = 0;         // 23040 f
    const size_t OFF_AVEC   = 23040;     // 48 f (+16 pad)
    const size_t OFF_S1     = 23104;     // 50000 f
    const size_t OFF_S3     = 73104;     // 50000 f
    const size_t OFF_CNT    = 123104;    // 50000 i
    const size_t OFF_BUCKET = 173104;    // N*CAP uint2 (8B aligned)
    const size_t NEED_BUCKET = OFF_BUCKET * 4 + (size_t)N_NODES * CAP * sizeof(uint2);

    float* wsf  = (float*)d_ws;
    float* Wrel = wsf + OFF_WREL;
    float* avec = wsf + OFF_AVEC;
    float* s1   = wsf + OFF_S1;
    float* s3   = wsf + OFF_S3;
    int* cnt    = (int*)(wsf + OFF_CNT);

    if (ws_size >= NEED_BUCKET) {
        uint2* bucket = (uint2*)(wsf + OFF_BUCKET);

        setup_kernel<<<PREP_BLOCKS + DOTS_BLOCKS + ZERO_BLOCKS + HZ_BLOCKS, 256, 0, stream>>>(
            Ws, Wa, weight, w_comp, h, Wrel, avec, s1, s3, cnt, hout);
        route_kernel<<<ROUTE_BLOCKS, 256, 0, stream>>>(
            h, he, src, dst, rel, Wrel, avec, s1, s3, cnt, bucket, hout);
        reduce_bmm_kernel<<<REDUCE_BLOCKS, 1024, 0, stream>>>(
            h, Wrel, s1, s3, bucket, cnt, hout);
    } else {
        hipMemsetAsync(d_out, 0, (size_t)out_size * sizeof(float), stream);
        int total = N_RELS * IN_DIM * OUT_DIM + 48;
        prep_kernel<<<(total + 255) / 256, 256, 0, stream>>>(Ws, Wa, weight, w_comp, Wrel, avec);
        edge_atomic_kernel<<<(N_EDGES + 255) / 256, 256, 0, stream>>>(
            h, he, src, dst, rel, Wrel, avec, hout);
    }
}

// Round 9
// 209.124 us; speedup vs baseline: 1.7717x; 1.1875x over previous
//
#include <hip/hip_runtime.h>

#define N_NODES 50000
#define N_EDGES 800000
#define IN_DIM 16
#define OUT_DIM 16
#define N_RELS 90
#define N_BASES 30

#define CAP 64          // 8B entries -> 512B/node row
#define RHALF_RELS 45   // rels per reduce half-block
#define LDS_STRIDE 260  // 256 + 4 pad; bank rotation +4/rel, 16B aligned

#define PREP_BLOCKS 91   // 91*256 = 23296 >= 23088
#define DOTS_BLOCKS 196  // 196*256 = 50176 >= 50000
#define ZERO_BLOCKS 196
#define HZ_BLOCKS 782    // 782*256 float4 >= 200000 float4 (zero hout)

#define ROUTE_BLOCKS 3125    // 1 edge/thread, 256/block
#define RNODES_PER_BLK 64    // reduce: 1024 thr / 16 lanes-per-node
#define REDUCE_PAIRS 782     // 782*64 = 50048 >= 50000; grid = 2x (rel halves)

__device__ __forceinline__ float4 shfl_xor4(float4 v, int m) {
    float4 r;
    r.x = __shfl_xor(v.x, m); r.y = __shfl_xor(v.y, m);
    r.z = __shfl_xor(v.z, m); r.w = __shfl_xor(v.w, m);
    return r;
}

// ---------------------------------------------------------------------------
// Setup: [0,91) prep Wrel+avec; [91,287) node dots s1/s3; [287,483) zero cnt;
// [483,1265) zero hout.
// ---------------------------------------------------------------------------
__global__ __launch_bounds__(256) void setup_kernel(
    const float* __restrict__ Ws,
    const float* __restrict__ Wa,
    const float* __restrict__ weight,
    const float* __restrict__ w_comp,
    const float* __restrict__ h,
    float* __restrict__ Wrel,
    float* __restrict__ avec,
    float* __restrict__ s1,
    float* __restrict__ s3,
    int* __restrict__ cnt,
    float* __restrict__ hout)
{
    int b = blockIdx.x;
    if (b < PREP_BLOCKS) {
        int f = b * 256 + threadIdx.x;
        if (f < N_RELS * IN_DIM * OUT_DIM) {
            int a   = f / (N_RELS * OUT_DIM);
            int rem = f % (N_RELS * OUT_DIM);
            int r   = rem / OUT_DIM;
            int o   = rem % OUT_DIM;
            float acc = 0.f;
            #pragma unroll
            for (int bb = 0; bb < N_BASES; ++bb)
                acc += w_comp[r * N_BASES + bb] * weight[a * (N_BASES * OUT_DIM) + bb * OUT_DIM + o];
            Wrel[f] = acc;
        } else if (f < N_RELS * IN_DIM * OUT_DIM + 48) {
            int g = f - N_RELS * IN_DIM * OUT_DIM;
            int k = g / IN_DIM;
            int i = g % IN_DIM;
            float acc = 0.f;
            #pragma unroll
            for (int o = 0; o < OUT_DIM; ++o)
                acc += Wa[k * OUT_DIM + o] * Ws[o * IN_DIM + i];
            avec[g] = acc;
        }
    } else if (b < PREP_BLOCKS + DOTS_BLOCKS) {
        __shared__ float la[48];
        if (threadIdx.x < 48) {
            int k = threadIdx.x / IN_DIM;
            int i = threadIdx.x % IN_DIM;
            float acc = 0.f;
            #pragma unroll
            for (int o = 0; o < OUT_DIM; ++o)
                acc += Wa[k * OUT_DIM + o] * Ws[o * IN_DIM + i];
            la[threadIdx.x] = acc;
        }
        __syncthreads();
        int n = (b - PREP_BLOCKS) * 256 + threadIdx.x;
        if (n >= N_NODES) return;
        const float4* p = (const float4*)(h + (size_t)n * IN_DIM);
        float d1 = 0.f, d3 = 0.f;
        #pragma unroll
        for (int i = 0; i < 4; ++i) {
            float4 v = p[i];
            d1 += v.x * la[4*i+0] + v.y * la[4*i+1] + v.z * la[4*i+2] + v.w * la[4*i+3];
            d3 += v.x * la[32+4*i+0] + v.y * la[32+4*i+1] + v.z * la[32+4*i+2] + v.w * la[32+4*i+3];
        }
        s1[n] = d1;
        s3[n] = d3;
    } else if (b < PREP_BLOCKS + DOTS_BLOCKS + ZERO_BLOCKS) {
        int n = (b - PREP_BLOCKS - DOTS_BLOCKS) * 256 + threadIdx.x;
        if (n < N_NODES) cnt[n] = 0;
    } else {
        int idx = (b - PREP_BLOCKS - DOTS_BLOCKS - ZERO_BLOCKS) * 256 + threadIdx.x;
        if (idx < N_NODES * OUT_DIM / 4) {
            float4 z = {0.f, 0.f, 0.f, 0.f};
            ((float4*)hout)[idx] = z;
        }
    }
}

// ---------------------------------------------------------------------------
// Route: 1 edge/thread, contiguous (coalesced idx + he stream). Only TWO
// random memory ops per edge: the cnt atomic and the 8B entry store.
// Entry carries pd = he[e] . a_edge; score finalized in reduce.
// ---------------------------------------------------------------------------
__global__ __launch_bounds__(256) void route_kernel(
    const float* __restrict__ h,
    const float* __restrict__ he,
    const int* __restrict__ src,
    const int* __restrict__ dst,
    const int* __restrict__ rel,
    const float* __restrict__ Wrel,
    const float* __restrict__ avec,
    const float* __restrict__ s1,
    const float* __restrict__ s3,
    int* __restrict__ cnt,
    uint2* __restrict__ bucket,
    float* __restrict__ hout)
{
    int e = blockIdx.x * 256 + threadIdx.x;
    if (e >= N_EDGES) return;
    int s = src[e], d = dst[e], r = rel[e];

    const float4* hep = (const float4*)(he + (size_t)e * IN_DIM);
    const float4* ap  = (const float4*)(avec + 16);
    float pd = 0.f;
    #pragma unroll
    for (int i = 0; i < 4; ++i) {
        float4 v = hep[i];
        float4 a = ap[i];
        pd += v.x * a.x + v.y * a.y + v.z * a.z + v.w * a.w;
    }

    int slot = atomicAdd(&cnt[d], 1);
    if (slot < CAP) {
        uint2 ent;
        ent.x = ((unsigned)r << 16) | (unsigned)s;   // s < 50000 < 2^16, r < 90
        ent.y = __float_as_uint(pd);
        bucket[(size_t)d * CAP + slot] = ent;
    } else {
        // rare/never: full message from global Wrel (L2-hot), full score here
        float score = s1[s] + s3[d] + pd;
        float hs[16];
        const float4* hp = (const float4*)(h + (size_t)s * IN_DIM);
        #pragma unroll
        for (int i = 0; i < 4; ++i) {
            float4 v = hp[i];
            hs[4*i+0] = v.x; hs[4*i+1] = v.y; hs[4*i+2] = v.z; hs[4*i+3] = v.w;
        }
        const float* W = Wrel + (size_t)r * 256;
        float* outp = hout + (size_t)d * OUT_DIM;
        #pragma unroll
        for (int o = 0; o < OUT_DIM; ++o) {
            float acc = 0.f;
            #pragma unroll
            for (int i = 0; i < IN_DIM; ++i) acc += hs[i] * W[i * OUT_DIM + o];
            atomicAdd(outp + o, acc * score);
        }
    }
}

// ---------------------------------------------------------------------------
// Reduce+BMM, RELATION-SPLIT: grid = 2x782; half = blockIdx&1, node range =
// blockIdx>>1 (pairs co-resident -> shared bucket lines in L1/L2). Each block
// stages 45 rels (46.8KB LDS) -> 2 blocks/CU = 32 waves/CU (round-6 was 1
// block @93.6KB = 16 waves; gather latency was exposed). A block processes
// only entries whose rel is in its half (entry loads are 8B broadcasts;
// h-gathers gated on the half test, so gather traffic total is unchanged).
// Both halves atomicAdd into pre-zeroed hout (skip if acc==0).
// Datapath identical to round 6: XOR-row quad transpose, score pre-scale,
// cross-stream butterfly (xor 4,8).
// ---------------------------------------------------------------------------
__global__ __launch_bounds__(1024) void reduce_bmm_kernel(
    const float* __restrict__ h,
    const float* __restrict__ Wrel,
    const float* __restrict__ s1,
    const float* __restrict__ s3,
    const uint2* __restrict__ bucket,
    const int* __restrict__ cnt,
    float* __restrict__ hout)
{
    extern __shared__ float lw[];   // [RHALF_RELS * LDS_STRIDE]
    const unsigned half = blockIdx.x & 1;
    const unsigned relbase = half * RHALF_RELS;

    for (int j = threadIdx.x; j < RHALF_RELS * 64; j += 1024) {
        int r = j >> 6;
        int w = j & 63;
        float4 v = ((const float4*)Wrel)[(relbase + r) * 64 + w];
        *(float4*)(lw + r * LDS_STRIDE + w * 4) = v;
    }
    __syncthreads();

    const int l = threadIdx.x & 15;
    const int q = l & 3;
    const int p = l >> 2;               // 0..3: entry stream
    const int n = (blockIdx.x >> 1) * RNODES_PER_BLK + (threadIdx.x >> 4);
    if (n >= N_NODES) return;

    int deg = cnt[n];
    int m = deg > CAP ? CAP : deg;
    const uint2* ep = bucket + (size_t)n * CAP;
    float s3n = s3[n];
    float4 acc = {0.f, 0.f, 0.f, 0.f};

    for (int j0 = 0; j0 < m; j0 += 8) {
        uint2 ent[2];
        float4 hq[2];
        float s1v[2];
        unsigned rh[2];
        bool use[2];

        // [1] entry loads (4 q-lanes share addr -> broadcast); in-half test
        //     (quad-uniform: same entry across the 4 q-lanes)
        #pragma unroll
        for (int k = 0; k < 2; ++k) {
            int j = j0 + p * 2 + k;
            bool val = (j < m);
            ent[k] = ep[val ? j : 0];
            rh[k] = (ent[k].x >> 16) - relbase;
            use[k] = val && (rh[k] < RHALF_RELS);
        }

        // [2] gathers only for in-half entries: h[src] 16B/lane + s1[src]
        #pragma unroll
        for (int k = 0; k < 2; ++k) {
            if (use[k]) {
                int sidx = ent[k].x & 0xFFFF;
                hq[k]  = *(const float4*)(h + (size_t)sidx * IN_DIM + q * 4);
                s1v[k] = s1[sidx];
            }
        }

        // [3] process (use[k] uniform across the 4 q-lanes of (n,p))
        #pragma unroll
        for (int k = 0; k < 2; ++k) {
            if (!use[k]) continue;
            float score = s1v[k] + s3n + __uint_as_float(ent[k].y);
            float4 hx = hq[k];
            hx.x *= score; hx.y *= score; hx.z *= score; hx.w *= score;

            const float* wb = lw + (size_t)rh[k] * LDS_STRIDE + q * 4;
            #pragma unroll
            for (int mm = 0; mm < 4; ++mm) {
                float4 vm = (mm == 0) ? hx : shfl_xor4(hx, mm);
                const float* wrow = wb + (((unsigned)(q ^ mm)) << 6);
                float4 w0 = *(const float4*)(wrow +  0);
                float4 w1 = *(const float4*)(wrow + 16);
                float4 w2 = *(const float4*)(wrow + 32);
                float4 w3 = *(const float4*)(wrow + 48);
                acc.x += vm.x*w0.x + vm.y*w1.x + vm.z*w2.x + vm.w*w3.x;
                acc.y += vm.x*w0.y + vm.y*w1.y + vm.z*w2.y + vm.w*w3.y;
                acc.z += vm.x*w0.z + vm.y*w1.z + vm.z*w2.z + vm.w*w3.z;
                acc.w += vm.x*w0.w + vm.y*w1.w + vm.z*w2.w + vm.w*w3.w;
            }
        }
    }

    // cross-stream butterfly (within the node's 16 lanes)
    acc.x += __shfl_xor(acc.x, 4); acc.y += __shfl_xor(acc.y, 4);
    acc.z += __shfl_xor(acc.z, 4); acc.w += __shfl_xor(acc.w, 4);
    acc.x += __shfl_xor(acc.x, 8); acc.y += __shfl_xor(acc.y, 8);
    acc.z += __shfl_xor(acc.z, 8); acc.w += __shfl_xor(acc.w, 8);

    // both halves contribute: atomicAdd into pre-zeroed hout; skipping a
    // zero-sum add is always safe (hout starts at 0)
    if (p == 0 && (acc.x != 0.f || acc.y != 0.f || acc.z != 0.f || acc.w != 0.f)) {
        float* outp = hout + (size_t)n * OUT_DIM + q * 4;
        atomicAdd(outp + 0, acc.x);
        atomicAdd(outp + 1, acc.y);
        atomicAdd(outp + 2, acc.z);
        atomicAdd(outp + 3, acc.w);
    }
}

// ===========================================================================
// Fallback (ws too small): direct atomic scatter (known-correct).
// ===========================================================================
__global__ __launch_bounds__(256) void prep_kernel(
    const float* __restrict__ Ws, const float* __restrict__ Wa,
    const float* __restrict__ weight, const float* __restrict__ w_comp,
    float* __restrict__ Wrel, float* __restrict__ avec)
{
    int f = blockIdx.x * blockDim.x + threadIdx.x;
    if (f < N_RELS * IN_DIM * OUT_DIM) {
        int a   = f / (N_RELS * OUT_DIM);
        int rem = f % (N_RELS * OUT_DIM);
        int r   = rem / OUT_DIM;
        int o   = rem % OUT_DIM;
        float acc = 0.f;
        #pragma unroll
        for (int b = 0; b < N_BASES; ++b)
            acc += w_comp[r * N_BASES + b] * weight[a * (N_BASES * OUT_DIM) + b * OUT_DIM + o];
        Wrel[f] = acc;
    } else if (f < N_RELS * IN_DIM * OUT_DIM + 48) {
        int g = f - N_RELS * IN_DIM * OUT_DIM;
        int k = g / IN_DIM;
        int i = g % IN_DIM;
        float acc = 0.f;
        #pragma unroll
        for (int o = 0; o < OUT_DIM; ++o)
            acc += Wa[k * OUT_DIM + o] * Ws[o * IN_DIM + i];
        avec[g] = acc;
    }
}

__global__ __launch_bounds__(256) void edge_atomic_kernel(
    const float* __restrict__ h,
    const float* __restrict__ he,
    const int* __restrict__ src,
    const int* __restrict__ dst,
    const int* __restrict__ rel,
    const float* __restrict__ Wrel,
    const float* __restrict__ avec,
    float* __restrict__ hout)
{
    int e = blockIdx.x * blockDim.x + threadIdx.x;
    if (e >= N_EDGES) return;
    int s = src[e], d = dst[e], r = rel[e];
    float hs[IN_DIM];
    const float4* p = (const float4*)(h + (size_t)s * IN_DIM);
    #pragma unroll
    for (int i = 0; i < 4; ++i) {
        float4 v = p[i];
        hs[4*i+0] = v.x; hs[4*i+1] = v.y; hs[4*i+2] = v.z; hs[4*i+3] = v.w;
    }
    float score = 0.f;
    #pragma unroll
    for (int i = 0; i < IN_DIM; ++i) score += hs[i] * avec[i];
    const float4* qe = (const float4*)(he + (size_t)e * IN_DIM);
    #pragma unroll
    for (int i = 0; i < 4; ++i) {
        float4 v = qe[i];
        score += v.x * avec[16+4*i] + v.y * avec[17+4*i] + v.z * avec[18+4*i] + v.w * avec[19+4*i];
    }
    const float4* pd = (const float4*)(h + (size_t)d * IN_DIM);
    #pragma unroll
    for (int i = 0; i < 4; ++i) {
        float4 v = pd[i];
        score += v.x * avec[32+4*i] + v.y * avec[33+4*i] + v.z * avec[34+4*i] + v.w * avec[35+4*i];
    }
    float acc[OUT_DIM];
    #pragma unroll
    for (int o = 0; o < OUT_DIM; ++o) acc[o] = 0.f;
    const float* W = Wrel + (size_t)r * 256;
    #pragma unroll
    for (int i = 0; i < IN_DIM; ++i) {
        float hv = hs[i];
        #pragma unroll
        for (int o = 0; o < OUT_DIM; ++o) acc[o] += hv * W[i * OUT_DIM + o];
    }
    float* outp = hout + (size_t)d * OUT_DIM;
    #pragma unroll
    for (int o = 0; o < OUT_DIM; ++o) atomicAdd(outp + o, acc[o] * score);
}

extern "C" void kernel_launch(void* const* d_in, const int* in_sizes, int n_in,
                              void* d_out, int out_size, void* d_ws, size_t ws_size,
                              hipStream_t stream) {
    const float* h      = (const float*)d_in[0];
    const float* he     = (const float*)d_in[1];
    const float* Ws     = (const float*)d_in[2];
    const float* Wa     = (const float*)d_in[3];
    const float* weight = (const float*)d_in[4];
    const float* w_comp = (const float*)d_in[5];
    const int*   src    = (const int*)d_in[6];
    const int*   dst    = (const int*)d_in[7];
    const int*   rel    = (const int*)d_in[8];
    float* hout = (float*)d_out;

    // ws layout (float offsets)
    const size_t OFF_WREL   = 0;         // 23040 f
    const size_t OFF_AVEC   = 23040;     // 48 f (+16 pad)
    const size_t OFF_S1     = 23104;     // 50000 f
    const size_t OFF_S3     = 73104;     // 50000 f
    const size_t OFF_CNT    = 123104;    // 50000 i
    const size_t OFF_BUCKET = 173104;    // N*CAP uint2 (8B aligned)
    const size_t NEED_BUCKET = OFF_BUCKET * 4 + (size_t)N_NODES * CAP * sizeof(uint2);

    float* wsf  = (float*)d_ws;
    float* Wrel = wsf + OFF_WREL;
    float* avec = wsf + OFF_AVEC;
    float* s1   = wsf + OFF_S1;
    float* s3   = wsf + OFF_S3;
    int* cnt    = (int*)(wsf + OFF_CNT);

    if (ws_size >= NEED_BUCKET) {
        uint2* bucket = (uint2*)(wsf + OFF_BUCKET);

        setup_kernel<<<PREP_BLOCKS + DOTS_BLOCKS + ZERO_BLOCKS + HZ_BLOCKS, 256, 0, stream>>>(
            Ws, Wa, weight, w_comp, h, Wrel, avec, s1, s3, cnt, hout);
        route_kernel<<<ROUTE_BLOCKS, 256, 0, stream>>>(
            h, he, src, dst, rel, Wrel, avec, s1, s3, cnt, bucket, hout);
        reduce_bmm_kernel<<<2 * REDUCE_PAIRS, 1024,
                            RHALF_RELS * LDS_STRIDE * sizeof(float), stream>>>(
            h, Wrel, s1, s3, bucket, cnt, hout);
    } else {
        hipMemsetAsync(d_out, 0, (size_t)out_size * sizeof(float), stream);
        int total = N_RELS * IN_DIM * OUT_DIM + 48;
        prep_kernel<<<(total + 255) / 256, 256, 0, stream>>>(Ws, Wa, weight, w_comp, Wrel, avec);
        edge_atomic_kernel<<<(N_EDGES + 255) / 256, 256, 0, stream>>>(
            h, he, src, dst, rel, Wrel, avec, hout);
    }
}